// Round 1
// baseline (25357.629 us; speedup 1.0000x reference)
//
#include <hip/hip_runtime.h>
#include <math.h>

// Problem constants (reference: B,T,D,H = 32,2048,512,512)
#define BB   32
#define TT   2048
#define DD   512
#define HH   512
#define G4H  2048   // 4*H

// ---------------------------------------------------------------------------
// Phase A: xw[t_local*32 + b][col] = sum_d X[b][t0+t][d] * W[d][col] + bias[col]
// fp32 tiled GEMM: 128x128 block tile, 16 K-step, 256 threads, 8x8 microtile.
// Also zeroes the 8 group barrier counters on the first chunk (t0==0).
// ---------------------------------------------------------------------------
__global__ __launch_bounds__(256, 2) void gemm_xw(
    const float* __restrict__ X, const float* __restrict__ Wm,
    const float* __restrict__ bias, float* __restrict__ xw,
    int t0, unsigned int* __restrict__ ctr)
{
    if (t0 == 0 && blockIdx.x == 0 && blockIdx.y == 0 && threadIdx.x < 8)
        ctr[threadIdx.x * 64] = 0u;

    __shared__ float As[16][128];
    __shared__ float Bs[16][128];

    const int tid  = threadIdx.x;
    const int row0 = blockIdx.y * 128;   // rows: (t_local, b) t-major
    const int col0 = blockIdx.x * 128;
    const int tx = tid & 15;
    const int ty = tid >> 4;

    float acc[8][8];
    #pragma unroll
    for (int i = 0; i < 8; ++i)
        #pragma unroll
        for (int j = 0; j < 8; ++j) acc[i][j] = 0.f;

    for (int k0 = 0; k0 < DD; k0 += 16) {
        // Load A tile (128 rows x 16 k), store transposed As[k][row]
        #pragma unroll
        for (int i = 0; i < 2; ++i) {
            int qa = tid + i * 256;          // 0..511 quads
            int r  = qa >> 2, kq = qa & 3;
            int grow = row0 + r;
            int b = grow & 31, tl = grow >> 5;
            const float4 a = *(const float4*)(X + ((size_t)b * TT + t0 + tl) * DD + k0 + kq * 4);
            As[kq*4+0][r] = a.x; As[kq*4+1][r] = a.y;
            As[kq*4+2][r] = a.z; As[kq*4+3][r] = a.w;

            int qb = tid + i * 256;
            int kb = qb >> 5, c4 = qb & 31;
            *(float4*)&Bs[kb][c4*4] =
                *(const float4*)(Wm + (size_t)(k0 + kb) * G4H + col0 + c4 * 4);
        }
        __syncthreads();

        #pragma unroll
        for (int k = 0; k < 16; ++k) {
            float a[8], b[8];
            #pragma unroll
            for (int i = 0; i < 8; ++i) a[i] = As[k][ty*8 + i];
            #pragma unroll
            for (int j = 0; j < 8; ++j) b[j] = Bs[k][tx*8 + j];
            #pragma unroll
            for (int i = 0; i < 8; ++i)
                #pragma unroll
                for (int j = 0; j < 8; ++j) acc[i][j] += a[i] * b[j];
        }
        __syncthreads();
    }

    // Epilogue: add bias, store
    #pragma unroll
    for (int i = 0; i < 8; ++i) {
        int grow = row0 + ty*8 + i;
        float* dst = xw + (size_t)grow * G4H + col0 + tx*8;
        #pragma unroll
        for (int j = 0; j < 8; j += 4) {
            float4 v;
            v.x = acc[i][j+0] + bias[col0 + tx*8 + j + 0];
            v.y = acc[i][j+1] + bias[col0 + tx*8 + j + 1];
            v.z = acc[i][j+2] + bias[col0 + tx*8 + j + 2];
            v.w = acc[i][j+3] + bias[col0 + tx*8 + j + 3];
            *(float4*)(dst + j) = v;
        }
    }
}

// ---------------------------------------------------------------------------
// Phase B: persistent recurrent kernel.
// Grid = 256 blocks x 256 threads. p = blockIdx%8 (batch group: batches 4p..4p+3),
// q = blockIdx/8 (unit group: hidden units 16q..16q+15 -> 64 gate columns).
// Wave w (0..3) = K-slice of 128; lane = (gate gi = lane>>4, unit u = lane&15).
// Recurrent weights held in 128 VGPRs/thread. h broadcast via LDS (uniform reads).
// Per-group 32-block barrier via agent-scope atomics; h_t written into d_out.
// ---------------------------------------------------------------------------
__global__ __launch_bounds__(256, 1) void lstm_rec(
    const float* __restrict__ W,
    const float* __restrict__ h_init,
    const float* __restrict__ xw,
    float* __restrict__ out,
    float* __restrict__ c_ws,
    unsigned int* __restrict__ ctr,
    int t0, int nT)
{
    __shared__ float hbuf[4][HH];       // h for the 4 batches of this group
    __shared__ float red[4][4][64];     // [kslice-wave][batch][lane]

    const int tid  = threadIdx.x;
    const int p    = blockIdx.x & 7;
    const int q    = blockIdx.x >> 3;
    const int w    = tid >> 6;          // wave id = K-slice (compute) = batch (reduce)
    const int lane = tid & 63;
    const int gi   = lane >> 4;
    const int u    = lane & 15;
    const int col  = gi * HH + q * 16 + u;   // gate column 0..2047

    // Persistent recurrent weights: W[512 + w*128 + kk][col]
    float wreg[128];
    {
        const float* Wp = W + (size_t)(DD + w * 128) * G4H + col;
        #pragma unroll
        for (int kk = 0; kk < 128; ++kk)
            wreg[kk] = Wp[(size_t)kk * G4H];
    }

    // c state: lanes 0..15 of wave w hold c[batch w][unit q*16+lane]
    float c = 0.f;
    if (t0 > 0 && lane < 16)
        c = c_ws[(size_t)(4 * p + w) * HH + q * 16 + lane];

    unsigned int* myctr = ctr + p * 64;

    for (int t = 0; t < nT; ++t) {
        const int gt = t0 + t;

        // Stage h(gt-1) into LDS: 4 x 512 floats, 2 float4 per thread, coalesced.
        #pragma unroll
        for (int i = 0; i < 2; ++i) {
            int qd = tid + i * 256;          // 0..511
            int b  = qd >> 7, k4 = qd & 127;
            const float* src = (gt == 0)
                ? (h_init + k4 * 4)
                : (out + ((size_t)(4 * p + b) * TT + (gt - 1)) * HH + k4 * 4);
            *(float4*)&hbuf[b][k4 * 4] = *(const float4*)src;
        }
        __syncthreads();

        // Prefetch the precomputed x-part for the reduce phase (batch = w).
        const float xg = xw[((size_t)t * BB + 4 * p + w) * G4H + col];

        // K-slice partial dot: acc[b] += sum_k wreg[k] * h[b][w*128+k]
        float a0 = 0.f, a1 = 0.f, a2 = 0.f, a3 = 0.f;
        const int kb = w * 128;
        #pragma unroll
        for (int k4 = 0; k4 < 32; ++k4) {
            const float4 h0 = *(const float4*)&hbuf[0][kb + k4 * 4];
            const float4 h1 = *(const float4*)&hbuf[1][kb + k4 * 4];
            const float4 h2 = *(const float4*)&hbuf[2][kb + k4 * 4];
            const float4 h3 = *(const float4*)&hbuf[3][kb + k4 * 4];
            const float w0 = wreg[k4*4+0], w1 = wreg[k4*4+1];
            const float w2 = wreg[k4*4+2], w3 = wreg[k4*4+3];
            a0 += w0*h0.x; a0 += w1*h0.y; a0 += w2*h0.z; a0 += w3*h0.w;
            a1 += w0*h1.x; a1 += w1*h1.y; a1 += w2*h1.z; a1 += w3*h1.w;
            a2 += w0*h2.x; a2 += w1*h2.y; a2 += w2*h2.z; a2 += w3*h2.w;
            a3 += w0*h3.x; a3 += w1*h3.y; a3 += w2*h3.z; a3 += w3*h3.w;
        }
        red[w][0][lane] = a0; red[w][1][lane] = a1;
        red[w][2][lane] = a2; red[w][3][lane] = a3;
        __syncthreads();

        // Wave w reduces batch w across the 4 K-slices, adds x-part (+bias).
        float g = red[0][w][lane] + red[1][w][lane]
                + red[2][w][lane] + red[3][w][lane] + xg;

        // Gather f,i,o,g for unit ul; lanes 0..15 do the elementwise update.
        const int ul = lane & 15;
        const float fv = __shfl(g, ul);
        const float iv = __shfl(g, ul + 16);
        const float ov = __shfl(g, ul + 32);
        const float gv = __shfl(g, ul + 48);
        if (lane < 16) {
            const float sf = 1.f / (1.f + __expf(-fv));
            const float si = 1.f / (1.f + __expf(-iv));
            const float so = 1.f / (1.f + __expf(-ov));
            const float tg = 1.f - 2.f / (__expf(2.f * gv) + 1.f);
            c = sf * c + si * tg;
            const float tc = 1.f - 2.f / (__expf(2.f * c) + 1.f);
            const float h = so * tc;
            out[((size_t)(4 * p + w) * TT + gt) * HH + q * 16 + lane] = h;
        }

        // Per-group barrier: 32 blocks. Release publishes h writes; acquire
        // invalidates stale lines before next step's h reads.
        __syncthreads();
        if (tid == 0) {
            __hip_atomic_fetch_add(myctr, 1u, __ATOMIC_RELEASE, __HIP_MEMORY_SCOPE_AGENT);
            const unsigned int tgt = 32u * (unsigned int)(gt + 1);
            while (__hip_atomic_load(myctr, __ATOMIC_ACQUIRE, __HIP_MEMORY_SCOPE_AGENT) < tgt) {}
        }
        __syncthreads();
    }

    // Spill c state for the next chunk.
    if (lane < 16)
        c_ws[(size_t)(4 * p + w) * HH + q * 16 + lane] = c;
}

// ---------------------------------------------------------------------------
extern "C" void kernel_launch(void* const* d_in, const int* in_sizes, int n_in,
                              void* d_out, int out_size, void* d_ws, size_t ws_size,
                              hipStream_t stream) {
    const float* x      = (const float*)d_in[0];
    // d_in[1] = input_paddings (unused)
    const float* W      = (const float*)d_in[2];
    const float* bias   = (const float*)d_in[3];
    const float* h_init = (const float*)d_in[4];
    float* out = (float*)d_out;

    // Pick the largest chunk of T whose xw buffer fits in ws
    // (xw chunk = CT*32*2048*4 bytes; + 2KB counters + 64KB c-state).
    static const int cand[] = {2048, 1024, 512, 256, 128, 64, 32, 16, 8, 4};
    int CT = 4;
    for (int i = 0; i < 10; ++i) {
        if ((size_t)cand[i] * BB * G4H * 4 + 2048 + 65536 <= ws_size) { CT = cand[i]; break; }
    }
    const size_t xw_bytes = (size_t)CT * BB * G4H * 4;
    float*        xw   = (float*)d_ws;
    unsigned int* ctr  = (unsigned int*)((char*)d_ws + xw_bytes);
    float*        c_ws = (float*)((char*)d_ws + xw_bytes + 2048);

    for (int t0 = 0; t0 < TT; t0 += CT) {
        dim3 g(G4H / 128, CT * BB / 128);
        gemm_xw<<<g, 256, 0, stream>>>(x, W, bias, xw, t0, ctr);
        lstm_rec<<<256, 256, 0, stream>>>(W, h_init, xw, out, c_ws, ctr, t0, CT);
    }
}

// Round 2
// 21881.412 us; speedup vs baseline: 1.1589x; 1.1589x over previous
//
#include <hip/hip_runtime.h>
#include <math.h>

// Problem constants (reference: B,T,D,H = 32,2048,512,512)
#define BB   32
#define TT   2048
#define DD   512
#define HH   512
#define G4H  2048   // 4*H

typedef float f32x32 __attribute__((ext_vector_type(32)));

// ---------------------------------------------------------------------------
// Phase A: xw[t_local*32 + b][col] = sum_d X[b][t0+t][d] * W[d][col] + bias[col]
// fp32 tiled GEMM: 128x128 block tile, 16 K-step, 256 threads, 8x8 microtile.
// Also zeroes the 8 group barrier counters on the first chunk (t0==0).
// ---------------------------------------------------------------------------
__global__ __launch_bounds__(256, 2) void gemm_xw(
    const float* __restrict__ X, const float* __restrict__ Wm,
    const float* __restrict__ bias, float* __restrict__ xw,
    int t0, unsigned int* __restrict__ ctr)
{
    if (t0 == 0 && blockIdx.x == 0 && blockIdx.y == 0 && threadIdx.x < 8)
        ctr[threadIdx.x * 64] = 0u;

    __shared__ float As[16][128];
    __shared__ float Bs[16][128];

    const int tid  = threadIdx.x;
    const int row0 = blockIdx.y * 128;   // rows: (t_local, b) t-major
    const int col0 = blockIdx.x * 128;
    const int tx = tid & 15;
    const int ty = tid >> 4;

    float acc[8][8];
    #pragma unroll
    for (int i = 0; i < 8; ++i)
        #pragma unroll
        for (int j = 0; j < 8; ++j) acc[i][j] = 0.f;

    for (int k0 = 0; k0 < DD; k0 += 16) {
        #pragma unroll
        for (int i = 0; i < 2; ++i) {
            int qa = tid + i * 256;          // 0..511 quads
            int r  = qa >> 2, kq = qa & 3;
            int grow = row0 + r;
            int b = grow & 31, tl = grow >> 5;
            const float4 a = *(const float4*)(X + ((size_t)b * TT + t0 + tl) * DD + k0 + kq * 4);
            As[kq*4+0][r] = a.x; As[kq*4+1][r] = a.y;
            As[kq*4+2][r] = a.z; As[kq*4+3][r] = a.w;

            int qb = tid + i * 256;
            int kb = qb >> 5, c4 = qb & 31;
            *(float4*)&Bs[kb][c4*4] =
                *(const float4*)(Wm + (size_t)(k0 + kb) * G4H + col0 + c4 * 4);
        }
        __syncthreads();

        #pragma unroll
        for (int k = 0; k < 16; ++k) {
            float a[8], b[8];
            #pragma unroll
            for (int i = 0; i < 8; ++i) a[i] = As[k][ty*8 + i];
            #pragma unroll
            for (int j = 0; j < 8; ++j) b[j] = Bs[k][tx*8 + j];
            #pragma unroll
            for (int i = 0; i < 8; ++i)
                #pragma unroll
                for (int j = 0; j < 8; ++j) acc[i][j] += a[i] * b[j];
        }
        __syncthreads();
    }

    #pragma unroll
    for (int i = 0; i < 8; ++i) {
        int grow = row0 + ty*8 + i;
        float* dst = xw + (size_t)grow * G4H + col0 + tx*8;
        #pragma unroll
        for (int j = 0; j < 8; j += 4) {
            float4 v;
            v.x = acc[i][j+0] + bias[col0 + tx*8 + j + 0];
            v.y = acc[i][j+1] + bias[col0 + tx*8 + j + 1];
            v.z = acc[i][j+2] + bias[col0 + tx*8 + j + 2];
            v.w = acc[i][j+3] + bias[col0 + tx*8 + j + 3];
            *(float4*)(dst + j) = v;
        }
    }
}

// ---------------------------------------------------------------------------
// Phase B: persistent recurrent kernel.
// Grid = 256 blocks x 256 threads. p = blockIdx%8 (batches 4p..4p+3),
// q = blockIdx/8 (hidden units 16q..16q+15 -> 64 gate columns).
// Wave w (0..3) = K-slice of 128; lane = (gate gi = lane>>4, unit u = lane&15).
// Recurrent weights held in 4 x f32x32 ext-vectors (128 VGPRs, cannot be
// demoted to scratch). W deliberately NOT __restrict__: the stores to `out`
// inside the loop make re-loading W inside the loop illegal, so the 128
// weight loads cannot be sunk/rematerialized into the t-loop.
// ---------------------------------------------------------------------------
__global__ __launch_bounds__(256, 1) void lstm_rec(
    const float* W,
    const float* __restrict__ h_init,
    const float* __restrict__ xw,
    float* __restrict__ out,
    float* __restrict__ c_ws,
    unsigned int* __restrict__ ctr,
    int t0, int nT)
{
    __shared__ float hbuf[4][HH];       // h for the 4 batches of this group
    __shared__ float red[4][4][64];     // [kslice-wave][batch][lane]

    const int tid  = threadIdx.x;
    const int p    = blockIdx.x & 7;
    const int q    = blockIdx.x >> 3;
    const int w    = tid >> 6;          // wave id = K-slice (compute) = batch (reduce)
    const int lane = tid & 63;
    const int gi   = lane >> 4;
    const int u    = lane & 15;
    const int col  = gi * HH + q * 16 + u;   // gate column 0..2047

    // Persistent recurrent weights in registers: W[512 + w*128 + k][col]
    f32x32 wv0, wv1, wv2, wv3;
    {
        const float* Wp = W + (size_t)(DD + w * 128) * G4H + col;
        #pragma unroll
        for (int kk = 0; kk < 32; ++kk) {
            wv0[kk] = Wp[(size_t)(kk +  0) * G4H];
            wv1[kk] = Wp[(size_t)(kk + 32) * G4H];
            wv2[kk] = Wp[(size_t)(kk + 64) * G4H];
            wv3[kk] = Wp[(size_t)(kk + 96) * G4H];
        }
    }

    // c state: lanes 0..15 of wave w hold c[batch w][unit q*16+lane]
    float c = 0.f;
    if (t0 > 0 && lane < 16)
        c = c_ws[(size_t)(4 * p + w) * HH + q * 16 + lane];

    unsigned int* myctr = ctr + p * 64;
    const int kb = w * 128;

    for (int t = 0; t < nT; ++t) {
        const int gt = t0 + t;

        // Issue the precomputed x-part load early (independent of staging).
        const float xg = xw[((size_t)t * BB + 4 * p + w) * G4H + col];

        // Stage h(gt-1) into LDS: 4 x 512 floats, 2 float4 per thread.
        #pragma unroll
        for (int i = 0; i < 2; ++i) {
            int qd = tid + i * 256;          // 0..511
            int b  = qd >> 7, k4 = qd & 127;
            const float* src = (gt == 0)
                ? (h_init + k4 * 4)
                : (out + ((size_t)(4 * p + b) * TT + (gt - 1)) * HH + k4 * 4);
            *(float4*)&hbuf[b][k4 * 4] = *(const float4*)src;
        }
        __syncthreads();

        // K-slice partial dot: acc[b] += sum_k w[k] * h[b][kb+k]
        float a0 = 0.f, a1 = 0.f, a2 = 0.f, a3 = 0.f;

#define KBLOCK(WV, OFF)                                                      \
        _Pragma("unroll")                                                    \
        for (int k4 = 0; k4 < 8; ++k4) {                                     \
            const float4 h0 = *(const float4*)&hbuf[0][kb + (OFF) + k4 * 4]; \
            const float4 h1 = *(const float4*)&hbuf[1][kb + (OFF) + k4 * 4]; \
            const float4 h2 = *(const float4*)&hbuf[2][kb + (OFF) + k4 * 4]; \
            const float4 h3 = *(const float4*)&hbuf[3][kb + (OFF) + k4 * 4]; \
            const float w0 = WV[k4*4+0], w1 = WV[k4*4+1];                    \
            const float w2 = WV[k4*4+2], w3 = WV[k4*4+3];                    \
            a0 += w0*h0.x; a0 += w1*h0.y; a0 += w2*h0.z; a0 += w3*h0.w;      \
            a1 += w0*h1.x; a1 += w1*h1.y; a1 += w2*h1.z; a1 += w3*h1.w;      \
            a2 += w0*h2.x; a2 += w1*h2.y; a2 += w2*h2.z; a2 += w3*h2.w;      \
            a3 += w0*h3.x; a3 += w1*h3.y; a3 += w2*h3.z; a3 += w3*h3.w;      \
        }
        KBLOCK(wv0,  0)
        KBLOCK(wv1, 32)
        KBLOCK(wv2, 64)
        KBLOCK(wv3, 96)
#undef KBLOCK

        red[w][0][lane] = a0; red[w][1][lane] = a1;
        red[w][2][lane] = a2; red[w][3][lane] = a3;
        __syncthreads();

        // Wave w reduces batch w across the 4 K-slices, adds x-part (+bias).
        float g = red[0][w][lane] + red[1][w][lane]
                + red[2][w][lane] + red[3][w][lane] + xg;

        // Gather f,i,o,g for unit ul; lanes 0..15 do the elementwise update.
        const int ul = lane & 15;
        const float fv = __shfl(g, ul);
        const float iv = __shfl(g, ul + 16);
        const float ov = __shfl(g, ul + 32);
        const float gv = __shfl(g, ul + 48);
        if (lane < 16) {
            const float sf = 1.f / (1.f + __expf(-fv));
            const float si = 1.f / (1.f + __expf(-iv));
            const float so = 1.f / (1.f + __expf(-ov));
            const float tg = 1.f - 2.f / (__expf(2.f * gv) + 1.f);
            c = sf * c + si * tg;
            const float tc = 1.f - 2.f / (__expf(2.f * c) + 1.f);
            const float h = so * tc;
            out[((size_t)(4 * p + w) * TT + gt) * HH + q * 16 + lane] = h;
        }

        // Per-group barrier: 32 blocks. Release publishes h writes; acquire
        // invalidates stale lines before next step's h reads.
        __syncthreads();
        if (tid == 0) {
            __hip_atomic_fetch_add(myctr, 1u, __ATOMIC_RELEASE, __HIP_MEMORY_SCOPE_AGENT);
            const unsigned int tgt = 32u * (unsigned int)(gt + 1);
            while (__hip_atomic_load(myctr, __ATOMIC_ACQUIRE, __HIP_MEMORY_SCOPE_AGENT) < tgt) {}
        }
        __syncthreads();
    }

    // Spill c state for the next chunk.
    if (lane < 16)
        c_ws[(size_t)(4 * p + w) * HH + q * 16 + lane] = c;
}

// ---------------------------------------------------------------------------
extern "C" void kernel_launch(void* const* d_in, const int* in_sizes, int n_in,
                              void* d_out, int out_size, void* d_ws, size_t ws_size,
                              hipStream_t stream) {
    const float* x      = (const float*)d_in[0];
    // d_in[1] = input_paddings (unused)
    const float* W      = (const float*)d_in[2];
    const float* bias   = (const float*)d_in[3];
    const float* h_init = (const float*)d_in[4];
    float* out = (float*)d_out;

    // Pick the largest chunk of T whose xw buffer fits in ws
    // (xw chunk = CT*32*2048*4 bytes; + 2KB counters + 64KB c-state).
    static const int cand[] = {2048, 1024, 512, 256, 128, 64, 32, 16, 8, 4};
    int CT = 4;
    for (int i = 0; i < 10; ++i) {
        if ((size_t)cand[i] * BB * G4H * 4 + 2048 + 65536 <= ws_size) { CT = cand[i]; break; }
    }
    const size_t xw_bytes = (size_t)CT * BB * G4H * 4;
    float*        xw   = (float*)d_ws;
    unsigned int* ctr  = (unsigned int*)((char*)d_ws + xw_bytes);
    float*        c_ws = (float*)((char*)d_ws + xw_bytes + 2048);

    for (int t0 = 0; t0 < TT; t0 += CT) {
        dim3 g(G4H / 128, CT * BB / 128);
        gemm_xw<<<g, 256, 0, stream>>>(x, W, bias, xw, t0, ctr);
        lstm_rec<<<256, 256, 0, stream>>>(W, h_init, xw, out, c_ws, ctr, t0, CT);
    }
}

// Round 3
// 21356.113 us; speedup vs baseline: 1.1874x; 1.0246x over previous
//
#include <hip/hip_runtime.h>
#include <math.h>

// Problem constants (reference: B,T,D,H = 32,2048,512,512)
#define BB   32
#define TT   2048
#define DD   512
#define HH   512
#define G4H  2048   // 4*H

typedef float f32x32 __attribute__((ext_vector_type(32)));

// ---------------------------------------------------------------------------
// Phase A: xw[t_local*32 + b][col] = sum_d X[b][t0+t][d] * W[d][col] + bias[col]
// fp32 tiled GEMM: 128x128 block tile, 16 K-step, 256 threads, 8x8 microtile.
// Also zeroes the 8 group barrier counters on the first chunk (t0==0).
// ---------------------------------------------------------------------------
__global__ __launch_bounds__(256, 2) void gemm_xw(
    const float* __restrict__ X, const float* __restrict__ Wm,
    const float* __restrict__ bias, float* __restrict__ xw,
    int t0, unsigned int* __restrict__ ctr)
{
    if (t0 == 0 && blockIdx.x == 0 && blockIdx.y == 0 && threadIdx.x < 8)
        ctr[threadIdx.x * 64] = 0u;

    __shared__ float As[16][128];
    __shared__ float Bs[16][128];

    const int tid  = threadIdx.x;
    const int row0 = blockIdx.y * 128;   // rows: (t_local, b) t-major
    const int col0 = blockIdx.x * 128;
    const int tx = tid & 15;
    const int ty = tid >> 4;

    float acc[8][8];
    #pragma unroll
    for (int i = 0; i < 8; ++i)
        #pragma unroll
        for (int j = 0; j < 8; ++j) acc[i][j] = 0.f;

    for (int k0 = 0; k0 < DD; k0 += 16) {
        #pragma unroll
        for (int i = 0; i < 2; ++i) {
            int qa = tid + i * 256;          // 0..511 quads
            int r  = qa >> 2, kq = qa & 3;
            int grow = row0 + r;
            int b = grow & 31, tl = grow >> 5;
            const float4 a = *(const float4*)(X + ((size_t)b * TT + t0 + tl) * DD + k0 + kq * 4);
            As[kq*4+0][r] = a.x; As[kq*4+1][r] = a.y;
            As[kq*4+2][r] = a.z; As[kq*4+3][r] = a.w;

            int qb = tid + i * 256;
            int kb = qb >> 5, c4 = qb & 31;
            *(float4*)&Bs[kb][c4*4] =
                *(const float4*)(Wm + (size_t)(k0 + kb) * G4H + col0 + c4 * 4);
        }
        __syncthreads();

        #pragma unroll
        for (int k = 0; k < 16; ++k) {
            float a[8], b[8];
            #pragma unroll
            for (int i = 0; i < 8; ++i) a[i] = As[k][ty*8 + i];
            #pragma unroll
            for (int j = 0; j < 8; ++j) b[j] = Bs[k][tx*8 + j];
            #pragma unroll
            for (int i = 0; i < 8; ++i)
                #pragma unroll
                for (int j = 0; j < 8; ++j) acc[i][j] += a[i] * b[j];
        }
        __syncthreads();
    }

    #pragma unroll
    for (int i = 0; i < 8; ++i) {
        int grow = row0 + ty*8 + i;
        float* dst = xw + (size_t)grow * G4H + col0 + tx*8;
        #pragma unroll
        for (int j = 0; j < 8; j += 4) {
            float4 v;
            v.x = acc[i][j+0] + bias[col0 + tx*8 + j + 0];
            v.y = acc[i][j+1] + bias[col0 + tx*8 + j + 1];
            v.z = acc[i][j+2] + bias[col0 + tx*8 + j + 2];
            v.w = acc[i][j+3] + bias[col0 + tx*8 + j + 3];
            *(float4*)(dst + j) = v;
        }
    }
}

// ---------------------------------------------------------------------------
// Phase B: persistent recurrent kernel.
// Grid = 256 blocks x 256 threads. p = blockIdx%8 (batches 4p..4p+3),
// q = blockIdx/8 (hidden units 16q..16q+15 -> 64 gate columns).
// Wave w (0..3) = K-slice of 128; lane = (gate gi = lane>>4, unit u = lane&15).
// Recurrent weights held in 4 x f32x32 ext-vectors. The empty asm with
// "+v" constraints makes them outputs of an opaque op: the compiler can no
// longer rematerialize them as per-step loads from W (the R1/R2 failure
// mode, legal because out/c_ws are __restrict__). VGPR budget at
// launch_bounds(256,1) is 512 -> ~200 live regs fit without spills.
// ---------------------------------------------------------------------------
__global__ __launch_bounds__(256, 1) void lstm_rec(
    const float* __restrict__ W,
    const float* __restrict__ h_init,
    const float* __restrict__ xw,
    float* __restrict__ out,
    float* __restrict__ c_ws,
    unsigned int* __restrict__ ctr,
    int t0, int nT)
{
    __shared__ float hbuf[4][HH];       // h for the 4 batches of this group
    __shared__ float red[4][4][64];     // [kslice-wave][batch][lane]

    const int tid  = threadIdx.x;
    const int p    = blockIdx.x & 7;
    const int q    = blockIdx.x >> 3;
    const int w    = tid >> 6;          // wave id = K-slice (compute) = batch (reduce)
    const int lane = tid & 63;
    const int gi   = lane >> 4;
    const int u    = lane & 15;
    const int col  = gi * HH + q * 16 + u;   // gate column 0..2047

    // Persistent recurrent weights in registers: W[512 + w*128 + k][col]
    f32x32 wv0, wv1, wv2, wv3;
    {
        const float* Wp = W + (size_t)(DD + w * 128) * G4H + col;
        #pragma unroll
        for (int kk = 0; kk < 32; ++kk) {
            wv0[kk] = Wp[(size_t)(kk +  0) * G4H];
            wv1[kk] = Wp[(size_t)(kk + 32) * G4H];
            wv2[kk] = Wp[(size_t)(kk + 64) * G4H];
            wv3[kk] = Wp[(size_t)(kk + 96) * G4H];
        }
    }
    // Opaque redefinition: blocks load-rematerialization into the t-loop.
    asm volatile("" : "+v"(wv0), "+v"(wv1), "+v"(wv2), "+v"(wv3));

    // c state: lanes 0..15 of wave w hold c[batch w][unit q*16+lane]
    float c = 0.f;
    if (t0 > 0 && lane < 16)
        c = c_ws[(size_t)(4 * p + w) * HH + q * 16 + lane];

    unsigned int* myctr = ctr + p * 64;
    const int kb = w * 128;

    for (int t = 0; t < nT; ++t) {
        const int gt = t0 + t;

        // Issue the precomputed x-part load early (independent of staging).
        const float xg = xw[((size_t)t * BB + 4 * p + w) * G4H + col];

        // Stage h(gt-1) into LDS: 4 x 512 floats, 2 float4 per thread.
        #pragma unroll
        for (int i = 0; i < 2; ++i) {
            int qd = tid + i * 256;          // 0..511
            int b  = qd >> 7, k4 = qd & 127;
            const float* src = (gt == 0)
                ? (h_init + k4 * 4)
                : (out + ((size_t)(4 * p + b) * TT + (gt - 1)) * HH + k4 * 4);
            *(float4*)&hbuf[b][k4 * 4] = *(const float4*)src;
        }
        __syncthreads();

        // K-slice partial dot: acc[b] += sum_k w[k] * h[b][kb+k]
        float a0 = 0.f, a1 = 0.f, a2 = 0.f, a3 = 0.f;

#define KBLOCK(WV, OFF)                                                      \
        _Pragma("unroll")                                                    \
        for (int k4 = 0; k4 < 8; ++k4) {                                     \
            const float4 h0 = *(const float4*)&hbuf[0][kb + (OFF) + k4 * 4]; \
            const float4 h1 = *(const float4*)&hbuf[1][kb + (OFF) + k4 * 4]; \
            const float4 h2 = *(const float4*)&hbuf[2][kb + (OFF) + k4 * 4]; \
            const float4 h3 = *(const float4*)&hbuf[3][kb + (OFF) + k4 * 4]; \
            const float w0 = WV[k4*4+0], w1 = WV[k4*4+1];                    \
            const float w2 = WV[k4*4+2], w3 = WV[k4*4+3];                    \
            a0 += w0*h0.x; a0 += w1*h0.y; a0 += w2*h0.z; a0 += w3*h0.w;      \
            a1 += w0*h1.x; a1 += w1*h1.y; a1 += w2*h1.z; a1 += w3*h1.w;      \
            a2 += w0*h2.x; a2 += w1*h2.y; a2 += w2*h2.z; a2 += w3*h2.w;      \
            a3 += w0*h3.x; a3 += w1*h3.y; a3 += w2*h3.z; a3 += w3*h3.w;      \
        }
        KBLOCK(wv0,  0)
        KBLOCK(wv1, 32)
        KBLOCK(wv2, 64)
        KBLOCK(wv3, 96)
#undef KBLOCK

        red[w][0][lane] = a0; red[w][1][lane] = a1;
        red[w][2][lane] = a2; red[w][3][lane] = a3;
        __syncthreads();

        // Wave w reduces batch w across the 4 K-slices, adds x-part (+bias).
        float g = red[0][w][lane] + red[1][w][lane]
                + red[2][w][lane] + red[3][w][lane] + xg;

        // Gather f,i,o,g for unit ul; lanes 0..15 do the elementwise update.
        const int ul = lane & 15;
        const float fv = __shfl(g, ul);
        const float iv = __shfl(g, ul + 16);
        const float ov = __shfl(g, ul + 32);
        const float gv = __shfl(g, ul + 48);
        if (lane < 16) {
            const float sf = 1.f / (1.f + __expf(-fv));
            const float si = 1.f / (1.f + __expf(-iv));
            const float so = 1.f / (1.f + __expf(-ov));
            const float tg = 1.f - 2.f / (__expf(2.f * gv) + 1.f);
            c = sf * c + si * tg;
            const float tc = 1.f - 2.f / (__expf(2.f * c) + 1.f);
            const float h = so * tc;
            out[((size_t)(4 * p + w) * TT + gt) * HH + q * 16 + lane] = h;
        }

        // Per-group barrier: 32 blocks. Release publishes h writes; acquire
        // invalidates stale lines before next step's h reads.
        __syncthreads();
        if (tid == 0) {
            __hip_atomic_fetch_add(myctr, 1u, __ATOMIC_RELEASE, __HIP_MEMORY_SCOPE_AGENT);
            const unsigned int tgt = 32u * (unsigned int)(gt + 1);
            while (__hip_atomic_load(myctr, __ATOMIC_ACQUIRE, __HIP_MEMORY_SCOPE_AGENT) < tgt) {}
        }
        __syncthreads();
    }

    // Spill c state for the next chunk.
    if (lane < 16)
        c_ws[(size_t)(4 * p + w) * HH + q * 16 + lane] = c;
}

// ---------------------------------------------------------------------------
extern "C" void kernel_launch(void* const* d_in, const int* in_sizes, int n_in,
                              void* d_out, int out_size, void* d_ws, size_t ws_size,
                              hipStream_t stream) {
    const float* x      = (const float*)d_in[0];
    // d_in[1] = input_paddings (unused)
    const float* W      = (const float*)d_in[2];
    const float* bias   = (const float*)d_in[3];
    const float* h_init = (const float*)d_in[4];
    float* out = (float*)d_out;

    // Pick the largest chunk of T whose xw buffer fits in ws
    // (xw chunk = CT*32*2048*4 bytes; + 2KB counters + 64KB c-state).
    static const int cand[] = {2048, 1024, 512, 256, 128, 64, 32, 16, 8, 4};
    int CT = 4;
    for (int i = 0; i < 10; ++i) {
        if ((size_t)cand[i] * BB * G4H * 4 + 2048 + 65536 <= ws_size) { CT = cand[i]; break; }
    }
    const size_t xw_bytes = (size_t)CT * BB * G4H * 4;
    float*        xw   = (float*)d_ws;
    unsigned int* ctr  = (unsigned int*)((char*)d_ws + xw_bytes);
    float*        c_ws = (float*)((char*)d_ws + xw_bytes + 2048);

    for (int t0 = 0; t0 < TT; t0 += CT) {
        dim3 g(G4H / 128, CT * BB / 128);
        gemm_xw<<<g, 256, 0, stream>>>(x, W, bias, xw, t0, ctr);
        lstm_rec<<<256, 256, 0, stream>>>(W, h_init, xw, out, c_ws, ctr, t0, CT);
    }
}